// Round 5
// baseline (587.092 us; speedup 1.0000x reference)
//
#include <hip/hip_runtime.h>
#include <hip/hip_bf16.h>
#include <cfloat>

// Problem constants
#define B_   8
#define C_   256
#define CR_  128
#define T_   16
#define HW_  784
#define THW_ 12544           // T_*HW_
#define N_   1024            // B_*CR_
#define KTOP 196

typedef __attribute__((ext_vector_type(8))) short short8;
typedef __attribute__((ext_vector_type(4))) float float4_;

// bf16 helpers (RN-even), header-independent
__device__ __forceinline__ unsigned short f2bf(float x) {
    unsigned int u = __float_as_uint(x);
    unsigned int r = u + 0x7fffu + ((u >> 16) & 1u);
    return (unsigned short)(r >> 16);
}
__device__ __forceinline__ float bf2f(unsigned short s) {
    return __uint_as_float(((unsigned int)s) << 16);
}

// lane XOR exchange: ds_swizzle (no address VGPR) when mask stays within the
// 32-lane group, ds_bpermute (via __shfl_xor) when bit5 is involved.
template<int MASK>
__device__ __forceinline__ float lane_xor_f(float x) {
    if constexpr (MASK <= 31) {
        return __int_as_float(__builtin_amdgcn_ds_swizzle(
            __float_as_int(x), (MASK << 10) | 0x1F));
    } else {
        return __shfl_xor(x, MASK, 64);
    }
}

// ---------------------------------------------------------------------------
// Kernel 0: prep (unchanged).
// ---------------------------------------------------------------------------
__global__ __launch_bounds__(256) void prep(
    const float* __restrict__ Wq, const float* __restrict__ Wk,
    const float* __restrict__ Wv, const float* __restrict__ Wr,
    const float* __restrict__ bq, const float* __restrict__ bk,
    const float* __restrict__ bv, const float* __restrict__ br,
    const float* __restrict__ gamma, const float* __restrict__ beta,
    const float* __restrict__ bn_mean, const float* __restrict__ bn_var,
    unsigned short* __restrict__ Whi, unsigned short* __restrict__ Wlo,
    unsigned short* __restrict__ Wrbf, float* __restrict__ bias3,
    float* __restrict__ A1, float* __restrict__ A2)
{
    int idx = blockIdx.x * 256 + threadIdx.x;
    if (idx < 384 * 256) {
        int o = idx >> 8, k = idx & 255;
        int m = o >> 7, r = o & 127;
        const float* W = (m == 0) ? Wq : (m == 1) ? Wk : Wv;
        float v = W[r * 256 + k];
        unsigned short h = f2bf(v);
        Whi[idx] = h;
        Wlo[idx] = f2bf(v - bf2f(h));
    }
    if (idx < 256 * 128) {
        Wrbf[idx] = f2bf(Wr[idx]);
    }
    if (idx < 384) {
        bias3[idx] = (idx < 128) ? bq[idx] : (idx < 256) ? bk[idx - 128] : bv[idx - 256];
    }
    if (idx < 256) {
        float sc = gamma[idx] * rsqrtf(bn_var[idx] + 1e-5f);
        A1[idx] = sc;
        A2[idx] = br[idx] * sc + beta[idx] - bn_mean[idx] * sc;
    }
}

// ---------------------------------------------------------------------------
// Kernel 1: QKV GEMM via bf16x3 MFMA — barrier-free, no LDS.
// A fragments (Whi/Wlo, k-contiguous) load directly from global (L2-resident);
// B (x) fragments load direct from global fp32 with in-register hi/lo split.
// grid (196, 8): (p-tile of 64, batch); wave w handles m in [96w, 96w+96).
// ---------------------------------------------------------------------------
__global__ __launch_bounds__(256) void gemm_qkv_mfma(
    const unsigned short* __restrict__ Whi, const unsigned short* __restrict__ Wlo,
    const float* __restrict__ x, const float* __restrict__ bias3,
    float* __restrict__ Qb, float* __restrict__ Kb, float* __restrict__ Vb)
{
    const int tid  = threadIdx.x;
    const int wave = tid >> 6;
    const int lane = tid & 63;
    const int quad = lane >> 4;
    const int l16  = lane & 15;
    const int p0   = blockIdx.x * 64;
    const int b    = blockIdx.y;
    const int mW   = wave * 96;

    float4_ acc[6][4];
#pragma unroll
    for (int i = 0; i < 6; i++)
#pragma unroll
        for (int j = 0; j < 4; j++) acc[i][j] = (float4_)0.f;

    const float* xb = x + (size_t)b * C_ * THW_;

    for (int k0 = 0; k0 < 256; k0 += 32) {
        // --- B fragments: direct global loads + hi/lo split ---
        short8 Bh[4], Bl[4];
#pragma unroll
        for (int nf = 0; nf < 4; nf++) {
            const float* bp = xb + (size_t)(k0 + quad * 8) * THW_ + p0 + nf * 16 + l16;
#pragma unroll
            for (int jj = 0; jj < 8; jj++) {
                float v = bp[(size_t)jj * THW_];
                unsigned short h = f2bf(v);
                Bh[nf][jj] = (short)h;
                Bl[nf][jj] = (short)f2bf(v - bf2f(h));
            }
        }

        // --- A fragments direct from global + MFMA ---
#pragma unroll
        for (int mf = 0; mf < 6; mf++) {
            size_t rowoff = (size_t)(mW + mf * 16 + l16) * 256 + k0 + quad * 8;
            short8 Ah = *(const short8*)&Whi[rowoff];
            short8 Al = *(const short8*)&Wlo[rowoff];
#pragma unroll
            for (int nf = 0; nf < 4; nf++) {
                acc[mf][nf] = __builtin_amdgcn_mfma_f32_16x16x32_bf16(Al, Bh[nf], acc[mf][nf], 0, 0, 0);
                acc[mf][nf] = __builtin_amdgcn_mfma_f32_16x16x32_bf16(Ah, Bl[nf], acc[mf][nf], 0, 0, 0);
                acc[mf][nf] = __builtin_amdgcn_mfma_f32_16x16x32_bf16(Ah, Bh[nf], acc[mf][nf], 0, 0, 0);
            }
        }
    }

    // --- epilogue: o = mW + mf*16 + quad*4 + r, p = p0 + nf*16 + l16 ---
#pragma unroll
    for (int mf = 0; mf < 6; mf++) {
#pragma unroll
        for (int r = 0; r < 4; r++) {
            int oo  = mW + mf * 16 + quad * 4 + r;
            int mat = oo >> 7;
            int cr  = oo & 127;
            float bi = bias3[oo];
            float* dst = ((mat == 0) ? Qb : (mat == 1) ? Kb : Vb)
                         + ((size_t)(b * 128 + cr)) * THW_ + p0 + l16;
#pragma unroll
            for (int nf = 0; nf < 4; nf++)
                dst[nf * 16] = acc[mf][nf][r] + bi;
        }
    }
}

// ---------------------------------------------------------------------------
// Kernel 2: per-row descending sort, uniform-direction bitonic, one wave/row.
// i = lane*16 + r. Reversal first step per stage (i <-> i^(k-1)) keeps all
// runs descending -> all in-register phases have compile-time direction.
// ---------------------------------------------------------------------------
template<int J>
__device__ __forceinline__ void cross_steps(float v[16], int lane) {
    if constexpr (J >= 16) {
        constexpr int JL = J >> 4;
        const bool kj = (lane & JL) == 0;
        float t[16];
#pragma unroll
        for (int r = 0; r < 16; r++) t[r] = lane_xor_f<JL>(v[r]);
#pragma unroll
        for (int r = 0; r < 16; r++) {
            float mx = fmaxf(v[r], t[r]), mn = fminf(v[r], t[r]);
            v[r] = kj ? mx : mn;
        }
        cross_steps<J / 2>(v, lane);
    }
}

__device__ __forceinline__ void inreg_steps(float v[16], int jmax) {
#pragma unroll
    for (int j = 8; j >= 1; j >>= 1) {
        if (j > jmax) continue;
#pragma unroll
        for (int r = 0; r < 16; r++) {
            if ((r & j) == 0) {
                int rp = r | j;
                float a = v[r], b2 = v[rp];
                v[r]  = fmaxf(a, b2);
                v[rp] = fminf(a, b2);
            }
        }
    }
}

template<int K>
__device__ __forceinline__ void stage_ge32(float v[16], int lane) {
    constexpr int LM = (K - 1) >> 4;
    const bool km = (lane & (K >> 5)) == 0;
    float t[16];
#pragma unroll
    for (int r = 0; r < 16; r++) t[r] = lane_xor_f<LM>(v[15 - r]);
#pragma unroll
    for (int r = 0; r < 16; r++) {
        float mx = fmaxf(v[r], t[r]), mn = fminf(v[r], t[r]);
        v[r] = km ? mx : mn;
    }
    cross_steps<K / 4>(v, lane);
    inreg_steps(v, 8);
}

__global__ __launch_bounds__(256) void topk_sort_wave(
    const float* __restrict__ Qb, const float* __restrict__ Kb,
    float* __restrict__ Qtk, float* __restrict__ Ktk)
{
    const int wave = threadIdx.x >> 6;
    const int lane = threadIdx.x & 63;
    const int gw   = blockIdx.x * 4 + wave;      // 0..32767
    const int mat  = gw >> 14;                   // 0: Q, 1: K
    const int row  = gw & 16383;
    const float* src = ((mat == 0) ? Qb : Kb) + (size_t)row * HW_;
    float* dst       = ((mat == 0) ? Qtk : Ktk) + (size_t)row * KTOP;

    float v[16];
    if (lane < 49) {
        const float4* s4 = (const float4*)(src + lane * 16);
#pragma unroll
        for (int q = 0; q < 4; q++) {
            float4 t = s4[q];
            v[q * 4 + 0] = t.x; v[q * 4 + 1] = t.y;
            v[q * 4 + 2] = t.z; v[q * 4 + 3] = t.w;
        }
    } else {
#pragma unroll
        for (int r = 0; r < 16; r++) v[r] = -FLT_MAX;
    }

    // stages k=2..16: fully in-register, compile-time directions
#pragma unroll
    for (int k = 2; k <= 16; k <<= 1) {
        // reversal step: r <-> r^(k-1), max kept at lower half
#pragma unroll
        for (int r = 0; r < 16; r++) {
            if ((r & (k >> 1)) == 0) {
                int rp = r ^ (k - 1);
                float a = v[r], b2 = v[rp];
                v[r]  = fmaxf(a, b2);
                v[rp] = fminf(a, b2);
            }
        }
        // steps j = k/4 .. 1
#pragma unroll
        for (int j = 8; j >= 1; j >>= 1) {
            if (j > (k >> 2)) continue;
#pragma unroll
            for (int r = 0; r < 16; r++) {
                if ((r & j) == 0) {
                    int rp = r | j;
                    float a = v[r], b2 = v[rp];
                    v[r]  = fmaxf(a, b2);
                    v[rp] = fminf(a, b2);
                }
            }
        }
    }

    // stages k=32..1024
    stage_ge32<32>(v, lane);
    stage_ge32<64>(v, lane);
    stage_ge32<128>(v, lane);
    stage_ge32<256>(v, lane);
    stage_ge32<512>(v, lane);
    stage_ge32<1024>(v, lane);

    // store top 196 = lanes 0..11 fully + lane 12 regs 0..3
    if (lane < 12) {
        float4* d4 = (float4*)(dst + lane * 16);
#pragma unroll
        for (int q = 0; q < 4; q++) {
            float4 t;
            t.x = v[q * 4 + 0]; t.y = v[q * 4 + 1];
            t.z = v[q * 4 + 2]; t.w = v[q * 4 + 3];
            d4[q] = t;
        }
    } else if (lane == 12) {
        float4 t;
        t.x = v[0]; t.y = v[1]; t.z = v[2]; t.w = v[3];
        *(float4*)(dst + 192) = t;
    }
}

// ---------------------------------------------------------------------------
// Kernel 3: corr + softmax (unchanged).
// ---------------------------------------------------------------------------
__global__ __launch_bounds__(256) void corr_softmax(
    const float* __restrict__ Qtk, const float* __restrict__ Ktk,
    float* __restrict__ attn)
{
    const int n = blockIdx.x;
    __shared__ float qs[T_ * KTOP];
    __shared__ float ks[T_ * KTOP];
    __shared__ float cm[T_][T_ + 1];
    __shared__ float mx[T_], sm[T_];
    const int tid = threadIdx.x;

    for (int i = tid; i < T_ * KTOP; i += 256) {
        qs[i] = Qtk[(size_t)n * T_ * KTOP + i];
        ks[i] = Ktk[(size_t)n * T_ * KTOP + i];
    }
    __syncthreads();

    const int t = tid >> 4, sidx = tid & 15;
    const float* qr = &qs[t * KTOP];
    const float* kr = &ks[sidx * KTOP];
    float c = 0.f;
#pragma unroll 4
    for (int i = 0; i < KTOP; i++) c += qr[i] * kr[i];
    cm[t][sidx] = c;
    __syncthreads();

    if (tid < T_) {
        float m = cm[tid][0];
        for (int i = 1; i < T_; i++) m = fmaxf(m, cm[tid][i]);
        mx[tid] = m;
    }
    __syncthreads();
    float e = expf(c - mx[t]);
    cm[t][sidx] = e;
    __syncthreads();
    if (tid < T_) {
        float ssum = 0.f;
        for (int i = 0; i < T_; i++) ssum += cm[tid][i];
        sm[tid] = ssum;
    }
    __syncthreads();
    attn[(size_t)n * 256 + tid] = e / sm[t];
}

// ---------------------------------------------------------------------------
// Kernel 4: apply attention -> yT[b][t*784+p][cr] bf16.
// Register-blocked: thread owns (crl, 4t x 4p); transposed attn tile in LDS
// so inner s-loop is two ds_read_b128 + 16 FMA.
// grid (49, 8): (p-window of 16, batch). cr chunks of 16.
// ---------------------------------------------------------------------------
__global__ __launch_bounds__(256) void apply_attn_T(
    const float* __restrict__ attn, const float* __restrict__ V,
    unsigned short* __restrict__ yT)
{
    const int pc = blockIdx.x;
    const int b  = blockIdx.y;
    const int p0 = pc * 16;
    const int tid = threadIdx.x;
    const int crl = tid & 15;
    const int g   = tid >> 4;       // 0..15
    const int t0  = (g & 3) * 4;
    const int pl0 = (g >> 2) * 4;

    __shared__ float atT[16][264];  // [crl][s*16 + t]  (264: 16B-aligned rows)
    __shared__ float vt[16][264];   // [crl][s*16 + p]

    for (int chunk = 0; chunk < 8; chunk++) {
        const int crbase = chunk * 16;
        for (int i = tid; i < 4096; i += 256) {
            int cr = i >> 8, t = (i >> 4) & 15, s = i & 15;
            atT[cr][s * 16 + t] =
                attn[((size_t)(b * 128 + crbase + cr)) * 256 + t * 16 + s];
        }
        for (int i = tid; i < 4096; i += 256) {
            int cr = i >> 8, s = (i >> 4) & 15, p = i & 15;
            vt[cr][s * 16 + p] =
                V[((size_t)(b * 128 + crbase + cr)) * THW_ + s * HW_ + p0 + p];
        }
        __syncthreads();

        float acc[4][4];
#pragma unroll
        for (int i = 0; i < 4; i++)
#pragma unroll
            for (int j = 0; j < 4; j++) acc[i][j] = 0.f;

#pragma unroll
        for (int s = 0; s < 16; s++) {
            float4 av = *(const float4*)&atT[crl][s * 16 + t0];
            float4 vv = *(const float4*)&vt[crl][s * 16 + pl0];
            float a0 = av.x, a1 = av.y, a2 = av.z, a3 = av.w;
            float b0 = vv.x, b1 = vv.y, b2 = vv.z, b3 = vv.w;
            acc[0][0] += a0 * b0; acc[0][1] += a0 * b1; acc[0][2] += a0 * b2; acc[0][3] += a0 * b3;
            acc[1][0] += a1 * b0; acc[1][1] += a1 * b1; acc[1][2] += a1 * b2; acc[1][3] += a1 * b3;
            acc[2][0] += a2 * b0; acc[2][1] += a2 * b1; acc[2][2] += a2 * b2; acc[2][3] += a2 * b3;
            acc[3][0] += a3 * b0; acc[3][1] += a3 * b1; acc[3][2] += a3 * b2; acc[3][3] += a3 * b3;
        }

        const int cr = crbase + crl;
#pragma unroll
        for (int ti = 0; ti < 4; ti++)
#pragma unroll
            for (int pi = 0; pi < 4; pi++)
                yT[((size_t)b * THW_ + (t0 + ti) * HW_ + p0 + pl0 + pi) * 128 + cr]
                    = f2bf(acc[ti][pi]);
        __syncthreads();
    }
}

// ---------------------------------------------------------------------------
// Kernel 5: reconstruct GEMM via bf16 MFMA, fused BN + residual (unchanged).
// grid (196, 8)
// ---------------------------------------------------------------------------
__global__ __launch_bounds__(256) void gemm_recon_mfma(
    const unsigned short* __restrict__ Wrbf, const unsigned short* __restrict__ yT,
    const float* __restrict__ A1, const float* __restrict__ A2,
    const float* __restrict__ x, float* __restrict__ out)
{
    const int tid  = threadIdx.x;
    const int wave = tid >> 6;
    const int lane = tid & 63;
    const int quad = lane >> 4;
    const int l16  = lane & 15;
    const int p0   = blockIdx.x * 64;
    const int b    = blockIdx.y;
    const int mW   = wave * 64;

    float4_ acc[4][4];
#pragma unroll
    for (int i = 0; i < 4; i++)
#pragma unroll
        for (int j = 0; j < 4; j++) acc[i][j] = (float4_)0.f;

    const unsigned short* yTb = yT + (size_t)b * THW_ * 128;

#pragma unroll
    for (int k0 = 0; k0 < 128; k0 += 32) {
        short8 Bf[4];
#pragma unroll
        for (int nf = 0; nf < 4; nf++)
            Bf[nf] = *(const short8*)&yTb[(size_t)(p0 + nf * 16 + l16) * 128 + k0 + quad * 8];
#pragma unroll
        for (int mf = 0; mf < 4; mf++) {
            short8 Af = *(const short8*)&Wrbf[(size_t)(mW + mf * 16 + l16) * 128 + k0 + quad * 8];
#pragma unroll
            for (int nf = 0; nf < 4; nf++)
                acc[mf][nf] = __builtin_amdgcn_mfma_f32_16x16x32_bf16(Af, Bf[nf], acc[mf][nf], 0, 0, 0);
        }
    }

#pragma unroll
    for (int mf = 0; mf < 4; mf++) {
#pragma unroll
        for (int r = 0; r < 4; r++) {
            int co = mW + mf * 16 + quad * 4 + r;
            float sc = A1[co], sh = A2[co];
            size_t base = ((size_t)b * 256 + co) * THW_ + p0 + l16;
#pragma unroll
            for (int nf = 0; nf < 4; nf++) {
                float xv = x[base + nf * 16];
                out[base + nf * 16] = acc[mf][nf][r] * sc + sh + xv;
            }
        }
    }
}

// ---------------------------------------------------------------------------
extern "C" void kernel_launch(void* const* d_in, const int* in_sizes, int n_in,
                              void* d_out, int out_size, void* d_ws, size_t ws_size,
                              hipStream_t stream)
{
    const float* x      = (const float*)d_in[0];
    const float* Wq     = (const float*)d_in[1];
    const float* bq     = (const float*)d_in[2];
    const float* Wk     = (const float*)d_in[3];
    const float* bk     = (const float*)d_in[4];
    const float* Wv     = (const float*)d_in[5];
    const float* bv     = (const float*)d_in[6];
    const float* Wr     = (const float*)d_in[7];
    const float* br     = (const float*)d_in[8];
    const float* gamma  = (const float*)d_in[9];
    const float* beta   = (const float*)d_in[10];
    const float* bn_mean= (const float*)d_in[11];
    const float* bn_var = (const float*)d_in[12];
    float* out = (float*)d_out;

    // d_out doubles as scratch for Q and K (exactly 2 * N_*THW_ floats)
    float* Qb = out;
    float* Kb = out + (size_t)N_ * THW_;

    // workspace layout
    char* ws = (char*)d_ws;
    float* Vb            = (float*)ws;                       ws += (size_t)N_ * THW_ * 4;      // 51.4 MB
    unsigned short* yT   = (unsigned short*)ws;              ws += (size_t)N_ * THW_ * 2;      // 25.7 MB
    float* Qtk           = (float*)ws;                       ws += (size_t)N_ * T_ * KTOP * 4;
    float* Ktk           = (float*)ws;                       ws += (size_t)N_ * T_ * KTOP * 4;
    float* attn          = (float*)ws;                       ws += (size_t)N_ * T_ * T_ * 4;
    unsigned short* Whi  = (unsigned short*)ws;              ws += 384 * 256 * 2;
    unsigned short* Wlo  = (unsigned short*)ws;              ws += 384 * 256 * 2;
    unsigned short* Wrbf = (unsigned short*)ws;              ws += 256 * 128 * 2;
    float* bias3         = (float*)ws;                       ws += 384 * 4;
    float* A1            = (float*)ws;                       ws += 256 * 4;
    float* A2            = (float*)ws;                       ws += 256 * 4;

    prep<<<dim3(384), 256, 0, stream>>>(Wq, Wk, Wv, Wr, bq, bk, bv, br,
                                        gamma, beta, bn_mean, bn_var,
                                        Whi, Wlo, Wrbf, bias3, A1, A2);
    gemm_qkv_mfma<<<dim3(196, 8), 256, 0, stream>>>(Whi, Wlo, x, bias3, Qb, Kb, Vb);
    topk_sort_wave<<<dim3(8192), 256, 0, stream>>>(Qb, Kb, Qtk, Ktk);
    corr_softmax<<<dim3(1024), 256, 0, stream>>>(Qtk, Ktk, attn);
    apply_attn_T<<<dim3(49, 8), 256, 0, stream>>>(attn, Vb, yT);
    gemm_recon_mfma<<<dim3(196, 8), 256, 0, stream>>>(Wrbf, yT, A1, A2, x, out);
}